// Round 8
// baseline (129.210 us; speedup 1.0000x reference)
//
#include <hip/hip_runtime.h>

// Problem constants (reference: B=8, T=24, N=1024, D=64, W=2) — all f32 I/O.
#define BB 8
#define TT 24
#define NN 1024
#define DD 64
// 12288 16-row tiles. One tile per WAVE, fully independent (no inter-step barriers,
// no prefetch chains): 3072 blocks x 4 waves. Occupancy is VGPR-capped; this round
// is a register-diet experiment targeting <=102 VGPR => 5 waves/SIMD = 20 waves/CU.

typedef float  f32x4  __attribute__((ext_vector_type(4)));  // 16B vector / MFMA C-D frag
typedef __bf16 bf16x8 __attribute__((ext_vector_type(8)));  // MFMA A/B operand

__global__ __launch_bounds__(256) void stgcn_kernel(
    const float* __restrict__ x,     // [B,T,N,D] f32
    const float* __restrict__ W1,    // [D,D]
    const float* __restrict__ b1,    // [D]
    const float* __restrict__ W2,    // [D,D]
    const float* __restrict__ b2,    // [D]
    const float* __restrict__ gamma, // [D]
    const float* __restrict__ beta,  // [D]
    const float* __restrict__ adj,   // [N, N*W]
    float* __restrict__ out)         // [B,T,N,D]
{
    const int tid  = threadIdx.x;
    const int lane = tid & 63;
    const int wv   = tid >> 6;
    const int m16  = lane & 15;
    const int quad = lane >> 4;
    const int e4   = quad * 4;
    const int q8   = quad * 8;

    // ---- LDS: weights (16 KB) + epilogue params (1 KB). 17 KB => LDS allows 9
    // blocks/CU; occupancy cap moves to VGPR, which is what we're tuning. ----
    __shared__ bf16x8 wlds[16][64];
    __shared__ f32x4  plds[4][16];

    for (int s = tid; s < 16 * 64; s += 256) {
        const int g  = s >> 6, l = s & 63;
        const int mat = g >> 3, et = (g >> 1) & 3, ks = g & 1;
        const int ms = l & 15, qs = l >> 4;
        const float* src = (mat ? W2 : W1) + (et * 16 + ms) * DD + ks * 32 + qs * 8;
        const f32x4 a  = *(const f32x4*)(src);
        const f32x4 bb = *(const f32x4*)(src + 4);
        bf16x8 f;
#pragma unroll
        for (int j = 0; j < 4; ++j) { f[j] = (__bf16)a[j]; f[j + 4] = (__bf16)bb[j]; }
        wlds[g][l] = f;
    }
    if (tid < 64) {
        const int arr = tid >> 4, j = tid & 15;
        const float* src = (arr == 0) ? b1 : (arr == 1) ? b2 : (arr == 2) ? gamma : beta;
        plds[arr][j] = *(const f32x4*)(src + j * 4);
    }
    __syncthreads();   // weights ready; no further barriers — waves run free

    // ---- This wave's single tile ----
    const int wid = blockIdx.x * 4 + wv;       // [0, 12288)
    const int t   = (wid >> 6) % TT;           // 64 tiles per (b,t) slab
    const int n   = (wid & 63) * 16 + m16;     // this lane's node / output row

    // adjacency diagonal coefficients (scattered 4B gathers, L2/L3-resident)
    const float c0 = adj[(size_t)n * (NN * 2) + n];
    const float c1 = adj[(size_t)n * (NN * 2) + NN + n];
    const float cb = c0 + c1;                  // bias coeff (applies even at t=0)
    const float c0d = (t > 0) ? c0 : 0.f;      // blend coeff (zero-pad at t=0)
    const ptrdiff_t poff = (t > 0) ? -(ptrdiff_t)(NN * DD) : 0;  // clamped prev row

    const float* xr = x + ((size_t)wid * 16 + m16) * DD;
    const float* xq = xr + poff;

    // ---- Load phase: 8 x b128 in flight (cur + prev rows for the MFMA operand) ----
    const f32x4 cc0 = *(const f32x4*)(xr + q8);
    const f32x4 cc1 = *(const f32x4*)(xr + q8 + 4);
    const f32x4 cc2 = *(const f32x4*)(xr + 32 + q8);
    const f32x4 cc3 = *(const f32x4*)(xr + 36 + q8);
    const f32x4 pp0 = *(const f32x4*)(xq + q8);
    const f32x4 pp1 = *(const f32x4*)(xq + q8 + 4);
    const f32x4 pp2 = *(const f32x4*)(xq + 32 + q8);
    const f32x4 pp3 = *(const f32x4*)(xq + 36 + q8);

    // blend xbar = c0*x_prev + c1*x_cur -> bf16 fragments (cc/pp die here)
    bf16x8 X0, X1;
#pragma unroll
    for (int j = 0; j < 4; ++j) {
        X0[j]     = (__bf16)(c0d * pp0[j] + c1 * cc0[j]);
        X0[j + 4] = (__bf16)(c0d * pp1[j] + c1 * cc1[j]);
        X1[j]     = (__bf16)(c0d * pp2[j] + c1 * cc2[j]);
        X1[j + 4] = (__bf16)(c0d * pp3[j] + c1 * cc3[j]);
    }

    // ---- MFMA (swapped operands): lane m16 owns output row m16 ----
    // acc{1,2}[et][r] = h[row=m16][e = et*16 + e4 + r]
    f32x4 acc1[4], acc2[4];
#pragma unroll
    for (int et = 0; et < 4; ++et) {
        acc1[et] = (f32x4){0.f, 0.f, 0.f, 0.f};
        acc2[et] = (f32x4){0.f, 0.f, 0.f, 0.f};
    }
#pragma unroll
    for (int et = 0; et < 4; ++et) {
        const bf16x8 w10 = wlds[et * 2 + 0][lane];
        const bf16x8 w11 = wlds[et * 2 + 1][lane];
        const bf16x8 w20 = wlds[8 + et * 2 + 0][lane];
        const bf16x8 w21 = wlds[8 + et * 2 + 1][lane];
        acc1[et] = __builtin_amdgcn_mfma_f32_16x16x32_bf16(w10, X0, acc1[et], 0, 0, 0);
        acc1[et] = __builtin_amdgcn_mfma_f32_16x16x32_bf16(w11, X1, acc1[et], 0, 0, 0);
        acc2[et] = __builtin_amdgcn_mfma_f32_16x16x32_bf16(w20, X0, acc2[et], 0, 0, 0);
        acc2[et] = __builtin_amdgcn_mfma_f32_16x16x32_bf16(w21, X1, acc2[et], 0, 0, 0);
    }

    // ---- Register-diet fence: keep the xe loads BELOW the MFMA/load phase so their
    // live range doesn't overlap cc/pp (peak VGPR is the occupancy control variable).
    // Lines are L1/L2-hot (cc loads touched the same 256B rows) so late issue is cheap.
    __builtin_amdgcn_sched_barrier(0);

    f32x4 xe[4];
#pragma unroll
    for (int et = 0; et < 4; ++et)
        xe[et] = *(const f32x4*)(xr + et * 16 + e4);

    // ---- Epilogue: bias, relu(a1*a2)+a1, +x, LayerNorm (params from LDS) ----
    float s = 0.f, s2 = 0.f;
#pragma unroll
    for (int et = 0; et < 4; ++et) {
        const f32x4 b1v = plds[0][et * 4 + quad];
        const f32x4 b2v = plds[1][et * 4 + quad];
#pragma unroll
        for (int r = 0; r < 4; ++r) {
            const float A1v = acc1[et][r] + cb * b1v[r];
            const float A2v = acc2[et][r] + cb * b2v[r];
            const float p   = A1v * A2v;
            const float full = (p > 0.f ? p : 0.f) + A1v;
            const float zz = full + xe[et][r];
            acc1[et][r] = zz;        // z overwrites acc in place
            s  += zz;
            s2 += zz * zz;
        }
    }

    // Row reduction across the 4 quads holding row m16
    s  += __shfl_xor(s, 16, 64);
    s2 += __shfl_xor(s2, 16, 64);
    s  += __shfl_xor(s, 32, 64);
    s2 += __shfl_xor(s2, 32, 64);

    const float mu  = s * (1.f / 64.f);
    const float var = s2 * (1.f / 64.f) - mu * mu;
    const float rs  = rsqrtf(var + 1e-5f);

    float* orow = out + ((size_t)wid * 16 + m16) * DD;
#pragma unroll
    for (int et = 0; et < 4; ++et) {
        const f32x4 gvv = plds[2][et * 4 + quad];
        const f32x4 bev = plds[3][et * 4 + quad];
        f32x4 o;
#pragma unroll
        for (int r = 0; r < 4; ++r)
            o[r] = (acc1[et][r] - mu) * rs * gvv[r] + bev[r];
        *(f32x4*)(orow + et * 16 + e4) = o;   // 16B coalesced store
    }
}

extern "C" void kernel_launch(void* const* d_in, const int* in_sizes, int n_in,
                              void* d_out, int out_size, void* d_ws, size_t ws_size,
                              hipStream_t stream) {
    const float* x     = (const float*)d_in[0];
    const float* W1    = (const float*)d_in[1];
    const float* b1    = (const float*)d_in[2];
    const float* W2    = (const float*)d_in[3];
    const float* b2    = (const float*)d_in[4];
    const float* gamma = (const float*)d_in[5];
    const float* beta  = (const float*)d_in[6];
    const float* adj   = (const float*)d_in[7];
    float* out = (float*)d_out;

    // 3072 blocks x 256 thr = 12288 waves, ONE tile each, fully independent.
    // LDS 17 KB (not the cap); VGPR diet targets 5 waves/SIMD = 20 waves/CU with
    // natural block turnover (no lockstep barriers, waves retire asynchronously).
    dim3 grid(3072), block(256);
    hipLaunchKernelGGL(stgcn_kernel, grid, block, 0, stream,
                       x, W1, b1, W2, b2, gamma, beta, adj, out);
}

// Round 10
// 120.246 us; speedup vs baseline: 1.0746x; 1.0746x over previous
//
#include <hip/hip_runtime.h>

// Problem constants (reference: B=8, T=24, N=1024, D=64, W=2) — all f32 I/O.
#define BB 8
#define TT 24
#define NN 1024
#define DD 64
#define CHAIN 6
// Grid: 8(b) x 16(64-row node chunks) x 4(t-chains of 6) = 512 blocks = exactly
// 2 blocks/CU (65KB LDS), ENTIRE GRID RESIDENT — no churn, no tail.

typedef float  f32x4  __attribute__((ext_vector_type(4)));  // 16B vector / MFMA C-D frag
typedef __bf16 bf16x8 __attribute__((ext_vector_type(8)));  // MFMA A/B operand

// Async global->LDS DMA, 16B/lane. vmcnt-tracked; drained by __syncthreads().
// LDS dest is wave-uniform base + lane*16 (linear) as required.
__device__ __forceinline__ void gload16(const void* g, void* l) {
    __builtin_amdgcn_global_load_lds(
        (const __attribute__((address_space(1))) void*)g,
        (__attribute__((address_space(3)))       void*)l, 16, 0, 0);
}

__global__ __launch_bounds__(256) void stgcn_kernel(
    const float* __restrict__ x,     // [B,T,N,D] f32
    const float* __restrict__ W1,    // [D,D]
    const float* __restrict__ b1,    // [D]
    const float* __restrict__ W2,    // [D,D]
    const float* __restrict__ b2,    // [D]
    const float* __restrict__ gamma, // [D]
    const float* __restrict__ beta,  // [D]
    const float* __restrict__ adj,   // [N, N*W]
    float* __restrict__ out)         // [B,T,N,D]
{
    const int tid  = threadIdx.x;
    const int lane = tid & 63;
    const int wv   = tid >> 6;
    const int m16  = lane & 15;
    const int quad = lane >> 4;
    const int e4   = quad * 4;

    __shared__ bf16x8 wlds[16][64];                 // 16 KB weight fragments
    __shared__ __align__(16) float xbuf[3][4096];   // 48 KB x TRIPLE-buffer (64 rows each)
    __shared__ f32x4  plds[4][16];                  //  1 KB b1,b2,gamma,beta

    // ---- Stage weight fragments + params in LDS (verified path, r7) ----
    for (int s = tid; s < 16 * 64; s += 256) {
        const int g  = s >> 6, l = s & 63;
        const int mat = g >> 3, et = (g >> 1) & 3, ks = g & 1;
        const int ms = l & 15, qs = l >> 4;
        const float* src = (mat ? W2 : W1) + (et * 16 + ms) * DD + ks * 32 + qs * 8;
        const f32x4 a  = *(const f32x4*)(src);
        const f32x4 bb = *(const f32x4*)(src + 4);
        bf16x8 f;
#pragma unroll
        for (int j = 0; j < 4; ++j) { f[j] = (__bf16)a[j]; f[j + 4] = (__bf16)bb[j]; }
        wlds[g][l] = f;
    }
    if (tid < 64) {
        const int arr = tid >> 4, j = tid & 15;
        const float* src = (arr == 0) ? b1 : (arr == 1) ? b2 : (arr == 2) ? gamma : beta;
        plds[arr][j] = *(const f32x4*)(src + j * 4);
    }

    // ---- Block decomposition: (b, 64-row chunk, 6-step t-chain) ----
    const int blk = blockIdx.x;
    const int b   = blk >> 6;
    const int rem = blk & 63;
    const int n6  = rem >> 2;
    const int tg  = rem & 3;
    const int t0  = tg * CHAIN;
    const int n0  = n6 * 64;

    // adjacency diag coefficients (node set invariant across the chain; once per wave)
    const int n = n0 + wv * 16 + m16;
    const float c0 = adj[(size_t)n * (NN * 2) + n];
    const float c1 = adj[(size_t)n * (NN * 2) + NN + n];
    const float cb = c0 + c1;                 // bias coeff (applies even at t=0)
    const float c00 = (t0 > 0) ? c0 : 0.f;    // step-0 blend coeff (zero pad at t=0)

    // ---- async stage of one 16KB x-tile into xbuf[s]; pre-swizzled source ----
    // LDS dest linear; linear byte D sources global byte D ^ ((D>>8 &7)<<4) (involution).
    auto stage = [&](int s, int t) {
        const char* gb = (const char*)(x + ((size_t)(b * TT + t) * NN + n0) * DD);
        char* lb = (char*)&xbuf[s][0];
#pragma unroll
        for (int i = 0; i < 4; ++i) {
            const int D = i * 4096 + tid * 16;
            const int S = D ^ (((D >> 8) & 7) << 4);
            gload16(gb + S, lb + D);
        }
    };

    // prologue: buf0 <- x(t0-1) (or x(t0) dummy when t0==0: blend coeff is 0),
    //           buf1 <- x(t0). Full drain once (also covers wlds/plds).
    stage(0, (t0 > 0) ? t0 - 1 : t0);
    stage(1, t0);
    __syncthreads();

    const int R   = wv * 16 + m16;       // row within the 64-row block tile
    const int RB  = R * 256;             // row byte offset in buffer
    const int SW  = (m16 & 7) << 4;      // read-side swizzle xor ((R&7)<<4; wv*16 ≡ 0 mod 8)
    const int q32 = quad * 32;

#pragma unroll
    for (int k = 0; k < CHAIN; ++k) {
        const int t = t0 + k;
        const float c0k = (k == 0) ? c00 : c0;
        const char* pbuf = (const char*)&xbuf[k % 3][0];        // x(t-1)
        const char* cbuf = (const char*)&xbuf[(k + 1) % 3][0];  // x(t)

        // ---- issue next stage FIRST: target buffer (k+2)%3 is disjoint from both
        // read buffers (its last readers finished before the PREVIOUS step's
        // barrier), so no mid-step barrier; latency hides under the whole step.
        if (k + 1 < CHAIN) stage((k + 2) % 3, t + 1);

        // ---- ds_read all fragments (lgkm only; compiler inserts waits at use) ----
        const f32x4 cc0 = *(const f32x4*)(cbuf + ((RB + q32      ) ^ SW));
        const f32x4 cc1 = *(const f32x4*)(cbuf + ((RB + q32 + 16 ) ^ SW));
        const f32x4 cc2 = *(const f32x4*)(cbuf + ((RB + 128 + q32) ^ SW));
        const f32x4 cc3 = *(const f32x4*)(cbuf + ((RB + 144 + q32) ^ SW));
        const f32x4 pp0 = *(const f32x4*)(pbuf + ((RB + q32      ) ^ SW));
        const f32x4 pp1 = *(const f32x4*)(pbuf + ((RB + q32 + 16 ) ^ SW));
        const f32x4 pp2 = *(const f32x4*)(pbuf + ((RB + 128 + q32) ^ SW));
        const f32x4 pp3 = *(const f32x4*)(pbuf + ((RB + 144 + q32) ^ SW));
        f32x4 xe[4];
#pragma unroll
        for (int et = 0; et < 4; ++et)
            xe[et] = *(const f32x4*)(cbuf + ((RB + et * 64 + quad * 16) ^ SW));

        // ---- blend xbar = c0*x_prev + c1*x_cur -> bf16 fragments ----
        bf16x8 X0, X1;
#pragma unroll
        for (int j = 0; j < 4; ++j) {
            X0[j]     = (__bf16)(c0k * pp0[j] + c1 * cc0[j]);
            X0[j + 4] = (__bf16)(c0k * pp1[j] + c1 * cc1[j]);
            X1[j]     = (__bf16)(c0k * pp2[j] + c1 * cc2[j]);
            X1[j + 4] = (__bf16)(c0k * pp3[j] + c1 * cc3[j]);
        }

        // ---- MFMA (swapped operands): lane m16 owns output row m16 ----
        f32x4 acc1[4], acc2[4];
#pragma unroll
        for (int et = 0; et < 4; ++et) {
            acc1[et] = (f32x4){0.f, 0.f, 0.f, 0.f};
            acc2[et] = (f32x4){0.f, 0.f, 0.f, 0.f};
        }
#pragma unroll
        for (int et = 0; et < 4; ++et) {
            const bf16x8 w10 = wlds[et * 2 + 0][lane];
            const bf16x8 w11 = wlds[et * 2 + 1][lane];
            const bf16x8 w20 = wlds[8 + et * 2 + 0][lane];
            const bf16x8 w21 = wlds[8 + et * 2 + 1][lane];
            acc1[et] = __builtin_amdgcn_mfma_f32_16x16x32_bf16(w10, X0, acc1[et], 0, 0, 0);
            acc1[et] = __builtin_amdgcn_mfma_f32_16x16x32_bf16(w11, X1, acc1[et], 0, 0, 0);
            acc2[et] = __builtin_amdgcn_mfma_f32_16x16x32_bf16(w20, X0, acc2[et], 0, 0, 0);
            acc2[et] = __builtin_amdgcn_mfma_f32_16x16x32_bf16(w21, X1, acc2[et], 0, 0, 0);
        }

        // ---- Epilogue: bias, relu(a1*a2)+a1, +x, LayerNorm (params from LDS) ----
        float s = 0.f, s2 = 0.f;
#pragma unroll
        for (int et = 0; et < 4; ++et) {
            const f32x4 b1v = plds[0][et * 4 + quad];
            const f32x4 b2v = plds[1][et * 4 + quad];
#pragma unroll
            for (int r = 0; r < 4; ++r) {
                const float A1v = acc1[et][r] + cb * b1v[r];
                const float A2v = acc2[et][r] + cb * b2v[r];
                const float p   = A1v * A2v;
                const float full = (p > 0.f ? p : 0.f) + A1v;
                const float zz = full + xe[et][r];
                acc1[et][r] = zz;
                s  += zz;
                s2 += zz * zz;
            }
        }

        s  += __shfl_xor(s, 16, 64);
        s2 += __shfl_xor(s2, 16, 64);
        s  += __shfl_xor(s, 32, 64);
        s2 += __shfl_xor(s2, 32, 64);

        const float mu  = s * (1.f / 64.f);
        const float var = s2 * (1.f / 64.f) - mu * mu;
        const float rs  = rsqrtf(var + 1e-5f);

        float* orow = out + ((size_t)(b * TT + t) * NN + n0 + R) * DD;
#pragma unroll
        for (int et = 0; et < 4; ++et) {
            const f32x4 gvv = plds[2][et * 4 + quad];
            const f32x4 bev = plds[3][et * 4 + quad];
            f32x4 o;
#pragma unroll
            for (int r = 0; r < 4; ++r)
                o[r] = (acc1[et][r] - mu) * rs * gvv[r] + bev[r];
            *(f32x4*)(orow + et * 16 + e4) = o;   // 16B coalesced store
        }

        // ---- ONE barrier per step. __syncthreads' implicit vmcnt(0) drain is
        // ordering-safe (r9's counted vmcnt(4) raced: compiler may interleave the
        // staging gloads with the stores, breaking the oldest-4 assumption). The
        // staging loads were issued a full step ago, so the drain is cheap.
        if (k + 1 < CHAIN) __syncthreads();
    }
}

extern "C" void kernel_launch(void* const* d_in, const int* in_sizes, int n_in,
                              void* d_out, int out_size, void* d_ws, size_t ws_size,
                              hipStream_t stream) {
    const float* x     = (const float*)d_in[0];
    const float* W1    = (const float*)d_in[1];
    const float* b1    = (const float*)d_in[2];
    const float* W2    = (const float*)d_in[3];
    const float* b2    = (const float*)d_in[4];
    const float* gamma = (const float*)d_in[5];
    const float* beta  = (const float*)d_in[6];
    const float* adj   = (const float*)d_in[7];
    float* out = (float*)d_out;

    // 512 blocks x 256 thr: 8(b) x 16(n-chunks) x 4(t-chains of 6). 65KB LDS ->
    // exactly 2 blocks/CU, whole grid resident. Triple-buffered async staging,
    // stage-at-step-top, ONE __syncthreads per step.
    dim3 grid(512), block(256);
    hipLaunchKernelGGL(stgcn_kernel, grid, block, 0, stream,
                       x, W1, b1, W2, b2, gamma, beta, adj, out);
}